// Round 13
// baseline (490.205 us; speedup 1.0000x reference)
//
#include <hip/hip_runtime.h>

#define NF 768
#define D1 10
#define D2 128

typedef __attribute__((ext_vector_type(8))) short bf16x8;
typedef __attribute__((ext_vector_type(16))) float f32x16;

static __device__ __forceinline__ float sigf(float v){ return 1.0f/(1.0f+__expf(-v)); }
static __device__ __forceinline__ float tanhfast(float v){ return 2.0f/(1.0f+__expf(-2.0f*v)) - 1.0f; }
static __device__ __forceinline__ short f2bf(float f){
    unsigned u = __float_as_uint(f);
    u += 0x7fffu + ((u>>16)&1u);
    return (short)(u>>16);
}

static __device__ __forceinline__ void gload16(const void* g, void* l){
    __builtin_amdgcn_global_load_lds(
        (const __attribute__((address_space(1))) unsigned int*)(unsigned long long)g,
        (__attribute__((address_space(3))) unsigned int*)(unsigned long long)l,
        16, 0, 0);
}

static __device__ __forceinline__ bf16x8 cvt8(float4 a, float4 b){
    unsigned u0,u1,u2,u3;
    asm("v_cvt_pk_bf16_f32 %0, %1, %2" : "=v"(u0) : "v"(a.x), "v"(a.y));
    asm("v_cvt_pk_bf16_f32 %0, %1, %2" : "=v"(u1) : "v"(a.z), "v"(a.w));
    asm("v_cvt_pk_bf16_f32 %0, %1, %2" : "=v"(u2) : "v"(b.x), "v"(b.y));
    asm("v_cvt_pk_bf16_f32 %0, %1, %2" : "=v"(u3) : "v"(b.z), "v"(b.w));
    union { unsigned u[4]; bf16x8 v; } r;
    r.u[0]=u0; r.u[1]=u1; r.u[2]=u2; r.u[3]=u3;
    return r.v;
}

// ---- degree counts ----
__global__ void k_deg(const int* __restrict__ dst, int* __restrict__ cnt, int E){
    int e = blockIdx.x*256 + threadIdx.x;
    if(e<E) atomicAdd(&cnt[dst[e]], 1);
}

// ---- scan + dinv, single block ----
__global__ __launch_bounds__(256) void k_scan(const int* __restrict__ cnt,
                                              int* __restrict__ rowptr, int* __restrict__ rowcur,
                                              float* __restrict__ dinv, int N, int E){
    __shared__ int part[256];
    int t = threadIdx.x;
    int C = (N+255)/256;
    int lo = t*C, hi = lo+C; if(hi>N) hi=N; if(lo>N) lo=N;
    int s=0;
    for(int i=lo;i<hi;i++) s += cnt[i];
    part[t]=s;
    __syncthreads();
    if(t==0){
        int run=0;
        for(int i=0;i<256;i++){ int v=part[i]; part[i]=run; run+=v; }
        rowptr[N]=E;
    }
    __syncthreads();
    int run = part[t];
    for(int i=lo;i<hi;i++){
        rowptr[i]=run; rowcur[i]=run; run += cnt[i];
        dinv[i] = rsqrtf((float)cnt[i] + 1.0f);
    }
}

__global__ void k_fill(const int* __restrict__ src, const int* __restrict__ dst,
                       const float* __restrict__ dinv, int* __restrict__ rowcur,
                       int* __restrict__ esrc, float* __restrict__ enorm, int E){
    int e = blockIdx.x*256 + threadIdx.x;
    if(e>=E) return;
    int s=src[e], d=dst[e];
    int pos = atomicAdd(&rowcur[d], 1);
    esrc[pos]=s;
    enorm[pos]=dinv[s]*dinv[d];
}

// ---- h1 = x @ W1 ----
__global__ __launch_bounds__(256) void k_h1(const float* __restrict__ x,
                                            const float* __restrict__ W1,
                                            float* __restrict__ h1, int N){
    __shared__ float wt[D1*NF];
    for(int idx=threadIdx.x; idx<NF*D1; idx+=256){
        int k=idx/D1, c=idx-k*D1;
        wt[c*NF+k]=W1[idx];
    }
    __syncthreads();
    int row = blockIdx.x*4 + (threadIdx.x>>6);
    int lane = threadIdx.x&63;
    if(row>=N) return;
    const float4* xr = (const float4*)(x + (size_t)row*NF);
    float acc[D1];
#pragma unroll
    for(int c=0;c<D1;c++) acc[c]=0.f;
#pragma unroll
    for(int i=0;i<3;i++){
        float4 v = xr[lane + 64*i];
#pragma unroll
        for(int c=0;c<D1;c++){
            float4 w = *(const float4*)&wt[c*NF + (lane+64*i)*4];
            acc[c] += v.x*w.x + v.y*w.y + v.z*w.z + v.w*w.w;
        }
    }
#pragma unroll
    for(int c=0;c<D1;c++){
        float v=acc[c];
#pragma unroll
        for(int off=32;off;off>>=1) v += __shfl_down(v,off,64);
        acc[c]=v;
    }
    if(lane==0){
#pragma unroll
        for(int c=0;c<D1;c++) h1[(size_t)row*D1+c]=acc[c];
    }
}

// ---- FUSED layer-1 gather + relu + hz = h @ W2. 2 nodes/block (2 waves). ----
__global__ __launch_bounds__(128) void k_gh(const float* __restrict__ h1,
        const int* __restrict__ rowptr, const int* __restrict__ esrc,
        const float* __restrict__ enorm, const float* __restrict__ dinv,
        const float* __restrict__ b1, const float* __restrict__ W2,
        float* __restrict__ hz, int N){
    __shared__ float w2s[D1*D2];
    int tid = threadIdx.x;
    for(int i=tid;i<D1*D2;i+=128) w2s[i]=W2[i];
    __syncthreads();
    int node = blockIdx.x*2 + (tid>>6);
    int lane = tid&63;
    if(node>=N) return;
    int e0=rowptr[node], e1=rowptr[node+1];
    float acc[D1];
#pragma unroll
    for(int c=0;c<D1;c++) acc[c]=0.f;
    for(int e=e0+lane; e<e1; e+=64){
        int s=esrc[e]; float w=enorm[e];
        const float* hr = h1 + (size_t)s*D1;
#pragma unroll
        for(int c=0;c<D1;c++) acc[c] += hr[c]*w;
    }
#pragma unroll
    for(int c=0;c<D1;c++){
        float v=acc[c];
#pragma unroll
        for(int off=32;off;off>>=1) v += __shfl_down(v,off,64);
        acc[c] = __shfl(v, 0, 64);       // broadcast reduced sum to all lanes
    }
    float di=dinv[node], d2=di*di;
    const float* hr = h1 + (size_t)node*D1;
    float h[D1];
#pragma unroll
    for(int c=0;c<D1;c++){
        float v = acc[c] + hr[c]*d2 + b1[c];
        h[c] = v>0.f ? v : 0.f;
    }
    float o0=0.f, o1=0.f;
#pragma unroll
    for(int k=0;k<D1;k++){
        o0 += h[k]*w2s[k*D2 + lane];
        o1 += h[k]*w2s[k*D2 + 64 + lane];
    }
    hz[(size_t)node*D2 + lane]      = o0;
    hz[(size_t)node*D2 + 64 + lane] = o1;
}

// ---- layer-2 CSR gather (fused zfin), fp32 z table ----
__global__ __launch_bounds__(128) void k_gath2(const float* __restrict__ hz,
        const int* __restrict__ rowptr, const int* __restrict__ esrc,
        const float* __restrict__ enorm, const float* __restrict__ dinv,
        const float* __restrict__ b2, float* __restrict__ zbf, int N){
    int n = blockIdx.x;
    int c = threadIdx.x;
    int e0 = rowptr[n], e1 = rowptr[n+1];
    float di = dinv[n];
    float acc = hz[(size_t)n*D2+c]*di*di + b2[c];
    int e = e0;
    for(; e+1<e1; e+=2){
        int s0=esrc[e], s1=esrc[e+1];
        float w0=enorm[e], w1=enorm[e+1];
        acc += hz[(size_t)s0*D2+c]*w0 + hz[(size_t)s1*D2+c]*w1;
    }
    if(e<e1) acc += hz[(size_t)esrc[e]*D2+c]*enorm[e];
    zbf[(size_t)n*D2+c] = acc;
}

// ---- B fragment image K=1024 (+ zero cnt) ----
__global__ void k_wimgB(const float* __restrict__ Wih, ushort* __restrict__ img,
                        int* __restrict__ cnt, int N){
    int gid = blockIdx.x*256 + threadIdx.x;        // 12*64*64 = 49152
    if(gid < N) cnt[gid] = 0;
    if(gid >= 12*64*64) return;
    int l = gid & 63;
    int ks16 = (gid>>6) & 63;
    int f = gid >> 12;
    int dd = l & 31, kb = l>>5;
    int wn = f/3, gi = f - wn*3;
    int gbase = (gi==0)?0:((gi==1)?256:384);
    int wrow = gbase + wn*32 + dd;
    int k = ks16*16 + kb*8;
    const float* p = Wih + (size_t)wrow*1024 + k;
    float4 v0=*(const float4*)p, v1=*(const float4*)(p+4);
    bf16x8 o;
    o[0]=f2bf(v0.x); o[1]=f2bf(v0.y); o[2]=f2bf(v0.z); o[3]=f2bf(v0.w);
    o[4]=f2bf(v1.x); o[5]=f2bf(v1.y); o[6]=f2bf(v1.z); o[7]=f2bf(v1.w);
    *(bf16x8*)(img + (size_t)gid*8) = o;
}

// ---- fused MFMA GEMM + LSTM partials. SINGLE-WAVE blocks: BM=64 rows x 96 cols
// (one i/g/o gate triple), bid = tile*4 + wn (siblings consecutive -> L2/L3 share A).
// Zero barriers: self-paced pipeline, counted vmcnt only. LDS 20KB -> 8 blocks/CU. ----
__global__ __launch_bounds__(64,2) void k_big(
    const float* __restrict__ remb, const ushort* __restrict__ img,
    const float* __restrict__ zbf, const float* __restrict__ b_ih,
    const float* __restrict__ b_hh, const int* __restrict__ trip,
    float* __restrict__ rowacc, int T)
{
    __shared__ ushort Ab[4*2*64*8];   // 8 KB: [slot][kh][row][8bf16]
    __shared__ ushort Bb[4*3*64*8];   // 12 KB: [slot][frag][lane][8bf16]
    int lane = threadIdx.x;
    int bid  = blockIdx.x;
    int tile = bid>>2, wn = bid&3;
    int t0 = tile*64;
    int l31 = lane&31, lh = lane>>5;

    // A source: lane == row
    int tc = t0 + lane; if(tc>=T) tc=T-1;
    const float* pzh = zbf + (size_t)trip[3*tc]*D2;
    const float* prm = remb + (size_t)tc*NF;
    const float* pzt = zbf + (size_t)trip[3*tc+2]*D2;
    const ushort* wb0 = img + ((size_t)((wn*3+0)*4096) + lane)*8;
    const ushort* wb1 = img + ((size_t)((wn*3+1)*4096) + lane)*8;
    const ushort* wb2 = img + ((size_t)((wn*3+2)*4096) + lane)*8;

    f32x16 acc[2][3];
    const f32x16 zer = {0,0,0,0,0,0,0,0,0,0,0,0,0,0,0,0};
#pragma unroll
    for(int m=0;m<2;m++)
#pragma unroll
        for(int g=0;g<3;g++) acc[m][g]=zer;

    float4 pa[4][4];

#define SRCP(s_) ((s_)<8 ? (pzh+(s_)*16) : ((s_)<56 ? (prm+((s_)-8)*16) : (pzt+((s_)-56)*16)))
#define PALOAD(s_) if((s_)<64){ const float* p_=SRCP(s_); \
    pa[(s_)&3][0]=*(const float4*)(p_);    pa[(s_)&3][1]=*(const float4*)(p_+4); \
    pa[(s_)&3][2]=*(const float4*)(p_+8);  pa[(s_)&3][3]=*(const float4*)(p_+12); }
#define BISSUE(s_) if((s_)<64){ \
    gload16(wb0+(size_t)(s_)*512, &Bb[(((s_)&3)*3+0)*512]); \
    gload16(wb1+(size_t)(s_)*512, &Bb[(((s_)&3)*3+1)*512]); \
    gload16(wb2+(size_t)(s_)*512, &Bb[(((s_)&3)*3+2)*512]); }
#define AWRITE(s_) if((s_)<64){ int sl_=(s_)&3; \
    *(bf16x8*)&Ab[((sl_*2+0)*64+lane)*8] = cvt8(pa[sl_][0], pa[sl_][1]); \
    *(bf16x8*)&Ab[((sl_*2+1)*64+lane)*8] = cvt8(pa[sl_][2], pa[sl_][3]); }
#define COMPUTE(s_) { int sl_=(s_)&3; \
    bf16x8 A0_ = *(const bf16x8*)&Ab[((sl_*2+lh)*64 + l31)*8]; \
    bf16x8 A1_ = *(const bf16x8*)&Ab[((sl_*2+lh)*64 + 32 + l31)*8]; \
    bf16x8 B0_ = *(const bf16x8*)&Bb[((sl_*3+0)*64 + lane)*8]; \
    bf16x8 B1_ = *(const bf16x8*)&Bb[((sl_*3+1)*64 + lane)*8]; \
    bf16x8 B2_ = *(const bf16x8*)&Bb[((sl_*3+2)*64 + lane)*8]; \
    __builtin_amdgcn_s_setprio(1); \
    acc[0][0]=__builtin_amdgcn_mfma_f32_32x32x16_bf16(A0_,B0_,acc[0][0],0,0,0); \
    acc[0][1]=__builtin_amdgcn_mfma_f32_32x32x16_bf16(A0_,B1_,acc[0][1],0,0,0); \
    acc[0][2]=__builtin_amdgcn_mfma_f32_32x32x16_bf16(A0_,B2_,acc[0][2],0,0,0); \
    acc[1][0]=__builtin_amdgcn_mfma_f32_32x32x16_bf16(A1_,B0_,acc[1][0],0,0,0); \
    acc[1][1]=__builtin_amdgcn_mfma_f32_32x32x16_bf16(A1_,B1_,acc[1][1],0,0,0); \
    acc[1][2]=__builtin_amdgcn_mfma_f32_32x32x16_bf16(A1_,B2_,acc[1][2],0,0,0); \
    __builtin_amdgcn_s_setprio(0); }

#define STEP(s_, W_) { \
    BISSUE((s_)+2) \
    __builtin_amdgcn_sched_barrier(0); \
    PALOAD((s_)+3) \
    __builtin_amdgcn_sched_barrier(0); \
    AWRITE((s_)+1) \
    asm volatile("s_waitcnt vmcnt(" W_ ")" ::: "memory"); \
    __builtin_amdgcn_sched_barrier(0); \
    COMPUTE(s_) \
}

    // prologue: pa(0..2), B(0..1), AWRITE(0)
    PALOAD(0) PALOAD(1) PALOAD(2)
    __builtin_amdgcn_sched_barrier(0);
    BISSUE(0) BISSUE(1)
    __builtin_amdgcn_sched_barrier(0);
    AWRITE(0)

    STEP(0 ,"10") STEP(1 ,"14")
    STEP(2 ,"18") STEP(3 ,"18") STEP(4 ,"18") STEP(5 ,"18") STEP(6 ,"18") STEP(7 ,"18")
    STEP(8 ,"18") STEP(9 ,"18") STEP(10,"18") STEP(11,"18") STEP(12,"18") STEP(13,"18")
    STEP(14,"18") STEP(15,"18") STEP(16,"18") STEP(17,"18") STEP(18,"18") STEP(19,"18")
    STEP(20,"18") STEP(21,"18") STEP(22,"18") STEP(23,"18") STEP(24,"18") STEP(25,"18")
    STEP(26,"18") STEP(27,"18") STEP(28,"18") STEP(29,"18") STEP(30,"18") STEP(31,"18")
    STEP(32,"18") STEP(33,"18") STEP(34,"18") STEP(35,"18") STEP(36,"18") STEP(37,"18")
    STEP(38,"18") STEP(39,"18") STEP(40,"18") STEP(41,"18") STEP(42,"18") STEP(43,"18")
    STEP(44,"18") STEP(45,"18") STEP(46,"18") STEP(47,"18") STEP(48,"18") STEP(49,"18")
    STEP(50,"18") STEP(51,"18") STEP(52,"18") STEP(53,"18") STEP(54,"18") STEP(55,"18")
    STEP(56,"18") STEP(57,"18") STEP(58,"18") STEP(59,"18") STEP(60,"18")
    STEP(61,"14") STEP(62,"7")  STEP(63,"0")
#undef STEP
#undef COMPUTE
#undef AWRITE
#undef BISSUE
#undef PALOAD
#undef SRCP

    // ---- epilogue: bias + LSTM + partial row-sums (global atomics) ----
    int d = wn*32 + l31;
    float bi=b_ih[d]+b_hh[d];
    float bg=b_ih[256+d]+b_hh[256+d];
    float bo=b_ih[384+d]+b_hh[384+d];
#pragma unroll
    for(int m=0;m<2;m++){
#pragma unroll
        for(int r=0;r<16;r++){
            int row = m*32 + (r&3)+8*(r>>2)+4*lh;
            int t = t0+row;
            float ov = 0.f;
            if(t<T){
                float ig = acc[m][0][r] + bi;
                float gg = acc[m][1][r] + bg;
                float og = acc[m][2][r] + bo;
                float cc = sigf(ig)*tanhfast(gg);
                ov = sigf(og)*tanhfast(cc);
            }
#pragma unroll
            for(int off=1; off<32; off<<=1) ov += __shfl_xor(ov, off, 64);
            if(l31==0 && t<T) atomicAdd(&rowacc[t], ov);
        }
    }
}

__global__ void k_sig(const float* __restrict__ rowacc, float* __restrict__ score, int T){
    int t = blockIdx.x*256 + threadIdx.x;
    if(t<T) score[t] = sigf(rowacc[t]);
}

extern "C" void kernel_launch(void* const* d_in, const int* in_sizes, int n_in,
                              void* d_out, int out_size, void* d_ws, size_t ws_size,
                              hipStream_t stream){
    const float* x    = (const float*)d_in[0];
    const float* remb = (const float*)d_in[1];
    const float* W1   = (const float*)d_in[2];
    const float* b1   = (const float*)d_in[3];
    const float* W2   = (const float*)d_in[4];
    const float* b2   = (const float*)d_in[5];
    const float* Wih  = (const float*)d_in[6];
    const float* b_ih = (const float*)d_in[8];
    const float* b_hh = (const float*)d_in[9];
    const int*   ei   = (const int*)d_in[10];
    const int*   trip = (const int*)d_in[11];
    float* score = (float*)d_out;

    const int N = in_sizes[0]/NF;       // 15000
    const int E = in_sizes[10]/2;       // 200000
    const int T = in_sizes[11]/3;       // 100000
    const int* src = ei;
    const int* dst = ei + E;

    float* ws = (float*)d_ws;
    size_t o = 0;
    ushort* img  = (ushort*)(ws+o); o += (size_t)12*64*64*8/2;   // 786 KB
    float* zbf   = ws+o;            o += (size_t)N*D2;           // fp32 z
    float* rowacc= ws+o;            o += (size_t)((T+7)&~7);
    int*   cnt    = (int*)(ws+o);   o += (size_t)((N+8)&~7);
    int*   rowptr = (int*)(ws+o);   o += (size_t)((N+8)&~7);
    int*   rowcur = (int*)(ws+o);   o += (size_t)((N+8)&~7);
    int*   esrc   = (int*)(ws+o);   o += (size_t)E;
    float* enorm  = ws+o;           o += (size_t)E;
    float* dinv   = ws+o;           o += (size_t)((N+7)&~7);
    float* h1     = ws+o;           o += (size_t)N*D1;
    float* hz     = ws+o;           o += (size_t)N*D2;
    (void)ws_size; (void)n_in; (void)out_size;

    hipMemsetAsync(rowacc, 0, (size_t)T*sizeof(float), stream);

    k_wimgB<<<dim3((12*64*64+255)/256), dim3(256), 0, stream>>>(Wih, img, cnt, N);
    k_deg  <<<dim3((E+255)/256), dim3(256), 0, stream>>>(dst, cnt, E);
    k_scan <<<dim3(1), dim3(256), 0, stream>>>(cnt, rowptr, rowcur, dinv, N, E);
    k_fill <<<dim3((E+255)/256), dim3(256), 0, stream>>>(src, dst, dinv, rowcur, esrc, enorm, E);
    k_h1   <<<dim3((N+3)/4), dim3(256), 0, stream>>>(x, W1, h1, N);
    k_gh   <<<dim3((N+1)/2), dim3(128), 0, stream>>>(h1, rowptr, esrc, enorm, dinv, b1, W2, hz, N);
    k_gath2<<<dim3(N), dim3(128), 0, stream>>>(hz, rowptr, esrc, enorm, dinv, b2, zbf, N);
    k_big  <<<dim3(((T+63)/64)*4), dim3(64), 0, stream>>>(remb, img, zbf, b_ih, b_hh, trip, rowacc, T);
    k_sig  <<<dim3((T+255)/256), dim3(256), 0, stream>>>(rowacc, score, T);
}

// Round 14
// 452.335 us; speedup vs baseline: 1.0837x; 1.0837x over previous
//
#include <hip/hip_runtime.h>

#define NF 768
#define D1 10
#define D2 128

typedef __attribute__((ext_vector_type(8))) short bf16x8;
typedef __attribute__((ext_vector_type(16))) float f32x16;

static __device__ __forceinline__ float sigf(float v){ return 1.0f/(1.0f+__expf(-v)); }
static __device__ __forceinline__ float tanhfast(float v){ return 2.0f/(1.0f+__expf(-2.0f*v)) - 1.0f; }
static __device__ __forceinline__ short f2bf(float f){
    unsigned u = __float_as_uint(f);
    u += 0x7fffu + ((u>>16)&1u);
    return (short)(u>>16);
}

static __device__ __forceinline__ void gload16(const void* g, void* l){
    __builtin_amdgcn_global_load_lds(
        (const __attribute__((address_space(1))) unsigned int*)(unsigned long long)g,
        (__attribute__((address_space(3))) unsigned int*)(unsigned long long)l,
        16, 0, 0);
}

static __device__ __forceinline__ bf16x8 cvt8(float4 a, float4 b){
    unsigned u0,u1,u2,u3;
    asm("v_cvt_pk_bf16_f32 %0, %1, %2" : "=v"(u0) : "v"(a.x), "v"(a.y));
    asm("v_cvt_pk_bf16_f32 %0, %1, %2" : "=v"(u1) : "v"(a.z), "v"(a.w));
    asm("v_cvt_pk_bf16_f32 %0, %1, %2" : "=v"(u2) : "v"(b.x), "v"(b.y));
    asm("v_cvt_pk_bf16_f32 %0, %1, %2" : "=v"(u3) : "v"(b.z), "v"(b.w));
    union { unsigned u[4]; bf16x8 v; } r;
    r.u[0]=u0; r.u[1]=u1; r.u[2]=u2; r.u[3]=u3;
    return r.v;
}

// ---- degree counts ----
__global__ void k_deg(const int* __restrict__ dst, int* __restrict__ cnt, int E){
    int e = blockIdx.x*256 + threadIdx.x;
    if(e<E) atomicAdd(&cnt[dst[e]], 1);
}

// ---- scan + dinv, single block ----
__global__ __launch_bounds__(256) void k_scan(const int* __restrict__ cnt,
                                              int* __restrict__ rowptr, int* __restrict__ rowcur,
                                              float* __restrict__ dinv, int N, int E){
    __shared__ int part[256];
    int t = threadIdx.x;
    int C = (N+255)/256;
    int lo = t*C, hi = lo+C; if(hi>N) hi=N; if(lo>N) lo=N;
    int s=0;
    for(int i=lo;i<hi;i++) s += cnt[i];
    part[t]=s;
    __syncthreads();
    if(t==0){
        int run=0;
        for(int i=0;i<256;i++){ int v=part[i]; part[i]=run; run+=v; }
        rowptr[N]=E;
    }
    __syncthreads();
    int run = part[t];
    for(int i=lo;i<hi;i++){
        rowptr[i]=run; rowcur[i]=run; run += cnt[i];
        dinv[i] = rsqrtf((float)cnt[i] + 1.0f);
    }
}

__global__ void k_fill(const int* __restrict__ src, const int* __restrict__ dst,
                       const float* __restrict__ dinv, int* __restrict__ rowcur,
                       int* __restrict__ esrc, float* __restrict__ enorm, int E){
    int e = blockIdx.x*256 + threadIdx.x;
    if(e>=E) return;
    int s=src[e], d=dst[e];
    int pos = atomicAdd(&rowcur[d], 1);
    esrc[pos]=s;
    enorm[pos]=dinv[s]*dinv[d];
}

// ---- h1 = x @ W1 ----
__global__ __launch_bounds__(256) void k_h1(const float* __restrict__ x,
                                            const float* __restrict__ W1,
                                            float* __restrict__ h1, int N){
    __shared__ float wt[D1*NF];
    for(int idx=threadIdx.x; idx<NF*D1; idx+=256){
        int k=idx/D1, c=idx-k*D1;
        wt[c*NF+k]=W1[idx];
    }
    __syncthreads();
    int row = blockIdx.x*4 + (threadIdx.x>>6);
    int lane = threadIdx.x&63;
    if(row>=N) return;
    const float4* xr = (const float4*)(x + (size_t)row*NF);
    float acc[D1];
#pragma unroll
    for(int c=0;c<D1;c++) acc[c]=0.f;
#pragma unroll
    for(int i=0;i<3;i++){
        float4 v = xr[lane + 64*i];
#pragma unroll
        for(int c=0;c<D1;c++){
            float4 w = *(const float4*)&wt[c*NF + (lane+64*i)*4];
            acc[c] += v.x*w.x + v.y*w.y + v.z*w.z + v.w*w.w;
        }
    }
#pragma unroll
    for(int c=0;c<D1;c++){
        float v=acc[c];
#pragma unroll
        for(int off=32;off;off>>=1) v += __shfl_down(v,off,64);
        acc[c]=v;
    }
    if(lane==0){
#pragma unroll
        for(int c=0;c<D1;c++) h1[(size_t)row*D1+c]=acc[c];
    }
}

// ---- FUSED layer-1 gather + relu + hz = h @ W2. 2 nodes/block (2 waves). ----
__global__ __launch_bounds__(128) void k_gh(const float* __restrict__ h1,
        const int* __restrict__ rowptr, const int* __restrict__ esrc,
        const float* __restrict__ enorm, const float* __restrict__ dinv,
        const float* __restrict__ b1, const float* __restrict__ W2,
        float* __restrict__ hz, int N){
    __shared__ float w2s[D1*D2];
    int tid = threadIdx.x;
    for(int i=tid;i<D1*D2;i+=128) w2s[i]=W2[i];
    __syncthreads();
    int node = blockIdx.x*2 + (tid>>6);
    int lane = tid&63;
    if(node>=N) return;
    int e0=rowptr[node], e1=rowptr[node+1];
    float acc[D1];
#pragma unroll
    for(int c=0;c<D1;c++) acc[c]=0.f;
    for(int e=e0+lane; e<e1; e+=64){
        int s=esrc[e]; float w=enorm[e];
        const float* hr = h1 + (size_t)s*D1;
#pragma unroll
        for(int c=0;c<D1;c++) acc[c] += hr[c]*w;
    }
#pragma unroll
    for(int c=0;c<D1;c++){
        float v=acc[c];
#pragma unroll
        for(int off=32;off;off>>=1) v += __shfl_down(v,off,64);
        acc[c] = __shfl(v, 0, 64);
    }
    float di=dinv[node], d2=di*di;
    const float* hr = h1 + (size_t)node*D1;
    float h[D1];
#pragma unroll
    for(int c=0;c<D1;c++){
        float v = acc[c] + hr[c]*d2 + b1[c];
        h[c] = v>0.f ? v : 0.f;
    }
    float o0=0.f, o1=0.f;
#pragma unroll
    for(int k=0;k<D1;k++){
        o0 += h[k]*w2s[k*D2 + lane];
        o1 += h[k]*w2s[k*D2 + 64 + lane];
    }
    hz[(size_t)node*D2 + lane]      = o0;
    hz[(size_t)node*D2 + 64 + lane] = o1;
}

// ---- layer-2 CSR gather (fused zfin), fp32 z table ----
__global__ __launch_bounds__(128) void k_gath2(const float* __restrict__ hz,
        const int* __restrict__ rowptr, const int* __restrict__ esrc,
        const float* __restrict__ enorm, const float* __restrict__ dinv,
        const float* __restrict__ b2, float* __restrict__ zbf, int N){
    int n = blockIdx.x;
    int c = threadIdx.x;
    int e0 = rowptr[n], e1 = rowptr[n+1];
    float di = dinv[n];
    float acc = hz[(size_t)n*D2+c]*di*di + b2[c];
    int e = e0;
    for(; e+1<e1; e+=2){
        int s0=esrc[e], s1=esrc[e+1];
        float w0=enorm[e], w1=enorm[e+1];
        acc += hz[(size_t)s0*D2+c]*w0 + hz[(size_t)s1*D2+c]*w1;
    }
    if(e<e1) acc += hz[(size_t)esrc[e]*D2+c]*enorm[e];
    zbf[(size_t)n*D2+c] = acc;
}

// ---- B fragment image K=1024 (+ zero cnt) ----
__global__ void k_wimgB(const float* __restrict__ Wih, ushort* __restrict__ img,
                        int* __restrict__ cnt, int N){
    int gid = blockIdx.x*256 + threadIdx.x;        // 12*64*64 = 49152
    if(gid < N) cnt[gid] = 0;
    if(gid >= 12*64*64) return;
    int l = gid & 63;
    int ks16 = (gid>>6) & 63;
    int f = gid >> 12;
    int dd = l & 31, kb = l>>5;
    int wn = f/3, gi = f - wn*3;
    int gbase = (gi==0)?0:((gi==1)?256:384);
    int wrow = gbase + wn*32 + dd;
    int k = ks16*16 + kb*8;
    const float* p = Wih + (size_t)wrow*1024 + k;
    float4 v0=*(const float4*)p, v1=*(const float4*)(p+4);
    bf16x8 o;
    o[0]=f2bf(v0.x); o[1]=f2bf(v0.y); o[2]=f2bf(v0.z); o[3]=f2bf(v0.w);
    o[4]=f2bf(v1.x); o[5]=f2bf(v1.y); o[6]=f2bf(v1.z); o[7]=f2bf(v1.w);
    *(bf16x8*)(img + (size_t)gid*8) = o;
}

// ---- fused MFMA GEMM + LSTM partials. Single-wave blocks, no barriers.
// XCD-aware sibling mapping: group of 32 bids covers 8 tiles (one per XCD),
// the 4 siblings of a tile = bids {g*32+x, +8, +16, +24} -> SAME XCD x
// -> A rows fetched from HBM once, 3 re-reads served by that XCD's L2. ----
__global__ __launch_bounds__(64,2) void k_big(
    const float* __restrict__ remb, const ushort* __restrict__ img,
    const float* __restrict__ zbf, const float* __restrict__ b_ih,
    const float* __restrict__ b_hh, const int* __restrict__ trip,
    float* __restrict__ rowacc, int T)
{
    __shared__ ushort Ab[4*2*64*8];   // 8 KB: [slot][kh][row][8bf16]
    __shared__ ushort Bb[4*3*64*8];   // 12 KB: [slot][frag][lane][8bf16]
    int lane = threadIdx.x;
    int bid  = blockIdx.x;
    int tile = (bid>>5)*8 + (bid&7);  // XCD-aware (bid%8 = XCD under round-robin)
    int wn   = (bid>>3)&3;
    int t0 = tile*64;
    if(t0 >= T) return;               // padding tiles (no barriers in kernel -> safe)
    int l31 = lane&31, lh = lane>>5;

    int tc = t0 + lane; if(tc>=T) tc=T-1;
    const float* pzh = zbf + (size_t)trip[3*tc]*D2;
    const float* prm = remb + (size_t)tc*NF;
    const float* pzt = zbf + (size_t)trip[3*tc+2]*D2;
    const ushort* wb0 = img + ((size_t)((wn*3+0)*4096) + lane)*8;
    const ushort* wb1 = img + ((size_t)((wn*3+1)*4096) + lane)*8;
    const ushort* wb2 = img + ((size_t)((wn*3+2)*4096) + lane)*8;

    f32x16 acc[2][3];
    const f32x16 zer = {0,0,0,0,0,0,0,0,0,0,0,0,0,0,0,0};
#pragma unroll
    for(int m=0;m<2;m++)
#pragma unroll
        for(int g=0;g<3;g++) acc[m][g]=zer;

    float4 pa[4][4];

#define SRCP(s_) ((s_)<8 ? (pzh+(s_)*16) : ((s_)<56 ? (prm+((s_)-8)*16) : (pzt+((s_)-56)*16)))
#define PALOAD(s_) if((s_)<64){ const float* p_=SRCP(s_); \
    pa[(s_)&3][0]=*(const float4*)(p_);    pa[(s_)&3][1]=*(const float4*)(p_+4); \
    pa[(s_)&3][2]=*(const float4*)(p_+8);  pa[(s_)&3][3]=*(const float4*)(p_+12); }
#define BISSUE(s_) if((s_)<64){ \
    gload16(wb0+(size_t)(s_)*512, &Bb[(((s_)&3)*3+0)*512]); \
    gload16(wb1+(size_t)(s_)*512, &Bb[(((s_)&3)*3+1)*512]); \
    gload16(wb2+(size_t)(s_)*512, &Bb[(((s_)&3)*3+2)*512]); }
#define AWRITE(s_) if((s_)<64){ int sl_=(s_)&3; \
    *(bf16x8*)&Ab[((sl_*2+0)*64+lane)*8] = cvt8(pa[sl_][0], pa[sl_][1]); \
    *(bf16x8*)&Ab[((sl_*2+1)*64+lane)*8] = cvt8(pa[sl_][2], pa[sl_][3]); }
#define COMPUTE(s_) { int sl_=(s_)&3; \
    bf16x8 A0_ = *(const bf16x8*)&Ab[((sl_*2+lh)*64 + l31)*8]; \
    bf16x8 A1_ = *(const bf16x8*)&Ab[((sl_*2+lh)*64 + 32 + l31)*8]; \
    bf16x8 B0_ = *(const bf16x8*)&Bb[((sl_*3+0)*64 + lane)*8]; \
    bf16x8 B1_ = *(const bf16x8*)&Bb[((sl_*3+1)*64 + lane)*8]; \
    bf16x8 B2_ = *(const bf16x8*)&Bb[((sl_*3+2)*64 + lane)*8]; \
    __builtin_amdgcn_s_setprio(1); \
    acc[0][0]=__builtin_amdgcn_mfma_f32_32x32x16_bf16(A0_,B0_,acc[0][0],0,0,0); \
    acc[0][1]=__builtin_amdgcn_mfma_f32_32x32x16_bf16(A0_,B1_,acc[0][1],0,0,0); \
    acc[0][2]=__builtin_amdgcn_mfma_f32_32x32x16_bf16(A0_,B2_,acc[0][2],0,0,0); \
    acc[1][0]=__builtin_amdgcn_mfma_f32_32x32x16_bf16(A1_,B0_,acc[1][0],0,0,0); \
    acc[1][1]=__builtin_amdgcn_mfma_f32_32x32x16_bf16(A1_,B1_,acc[1][1],0,0,0); \
    acc[1][2]=__builtin_amdgcn_mfma_f32_32x32x16_bf16(A1_,B2_,acc[1][2],0,0,0); \
    __builtin_amdgcn_s_setprio(0); }

#define STEP(s_, W_) { \
    BISSUE((s_)+2) \
    __builtin_amdgcn_sched_barrier(0); \
    PALOAD((s_)+3) \
    __builtin_amdgcn_sched_barrier(0); \
    AWRITE((s_)+1) \
    asm volatile("s_waitcnt vmcnt(" W_ ")" ::: "memory"); \
    __builtin_amdgcn_sched_barrier(0); \
    COMPUTE(s_) \
}

    PALOAD(0) PALOAD(1) PALOAD(2)
    __builtin_amdgcn_sched_barrier(0);
    BISSUE(0) BISSUE(1)
    __builtin_amdgcn_sched_barrier(0);
    AWRITE(0)

    STEP(0 ,"10") STEP(1 ,"14")
    STEP(2 ,"18") STEP(3 ,"18") STEP(4 ,"18") STEP(5 ,"18") STEP(6 ,"18") STEP(7 ,"18")
    STEP(8 ,"18") STEP(9 ,"18") STEP(10,"18") STEP(11,"18") STEP(12,"18") STEP(13,"18")
    STEP(14,"18") STEP(15,"18") STEP(16,"18") STEP(17,"18") STEP(18,"18") STEP(19,"18")
    STEP(20,"18") STEP(21,"18") STEP(22,"18") STEP(23,"18") STEP(24,"18") STEP(25,"18")
    STEP(26,"18") STEP(27,"18") STEP(28,"18") STEP(29,"18") STEP(30,"18") STEP(31,"18")
    STEP(32,"18") STEP(33,"18") STEP(34,"18") STEP(35,"18") STEP(36,"18") STEP(37,"18")
    STEP(38,"18") STEP(39,"18") STEP(40,"18") STEP(41,"18") STEP(42,"18") STEP(43,"18")
    STEP(44,"18") STEP(45,"18") STEP(46,"18") STEP(47,"18") STEP(48,"18") STEP(49,"18")
    STEP(50,"18") STEP(51,"18") STEP(52,"18") STEP(53,"18") STEP(54,"18") STEP(55,"18")
    STEP(56,"18") STEP(57,"18") STEP(58,"18") STEP(59,"18") STEP(60,"18")
    STEP(61,"14") STEP(62,"7")  STEP(63,"0")
#undef STEP
#undef COMPUTE
#undef AWRITE
#undef BISSUE
#undef PALOAD
#undef SRCP

    // ---- epilogue: bias + LSTM + partial row-sums (global atomics) ----
    int d = wn*32 + l31;
    float bi=b_ih[d]+b_hh[d];
    float bg=b_ih[256+d]+b_hh[256+d];
    float bo=b_ih[384+d]+b_hh[384+d];
#pragma unroll
    for(int m=0;m<2;m++){
#pragma unroll
        for(int r=0;r<16;r++){
            int row = m*32 + (r&3)+8*(r>>2)+4*lh;
            int t = t0+row;
            float ov = 0.f;
            if(t<T){
                float ig = acc[m][0][r] + bi;
                float gg = acc[m][1][r] + bg;
                float og = acc[m][2][r] + bo;
                float cc = sigf(ig)*tanhfast(gg);
                ov = sigf(og)*tanhfast(cc);
            }
#pragma unroll
            for(int off=1; off<32; off<<=1) ov += __shfl_xor(ov, off, 64);
            if(l31==0 && t<T) atomicAdd(&rowacc[t], ov);
        }
    }
}

__global__ void k_sig(const float* __restrict__ rowacc, float* __restrict__ score, int T){
    int t = blockIdx.x*256 + threadIdx.x;
    if(t<T) score[t] = sigf(rowacc[t]);
}

extern "C" void kernel_launch(void* const* d_in, const int* in_sizes, int n_in,
                              void* d_out, int out_size, void* d_ws, size_t ws_size,
                              hipStream_t stream){
    const float* x    = (const float*)d_in[0];
    const float* remb = (const float*)d_in[1];
    const float* W1   = (const float*)d_in[2];
    const float* b1   = (const float*)d_in[3];
    const float* W2   = (const float*)d_in[4];
    const float* b2   = (const float*)d_in[5];
    const float* Wih  = (const float*)d_in[6];
    const float* b_ih = (const float*)d_in[8];
    const float* b_hh = (const float*)d_in[9];
    const int*   ei   = (const int*)d_in[10];
    const int*   trip = (const int*)d_in[11];
    float* score = (float*)d_out;

    const int N = in_sizes[0]/NF;       // 15000
    const int E = in_sizes[10]/2;       // 200000
    const int T = in_sizes[11]/3;       // 100000
    const int* src = ei;
    const int* dst = ei + E;

    float* ws = (float*)d_ws;
    size_t o = 0;
    ushort* img  = (ushort*)(ws+o); o += (size_t)12*64*64*8/2;   // 786 KB
    float* zbf   = ws+o;            o += (size_t)N*D2;           // fp32 z
    float* rowacc= ws+o;            o += (size_t)((T+7)&~7);
    int*   cnt    = (int*)(ws+o);   o += (size_t)((N+8)&~7);
    int*   rowptr = (int*)(ws+o);   o += (size_t)((N+8)&~7);
    int*   rowcur = (int*)(ws+o);   o += (size_t)((N+8)&~7);
    int*   esrc   = (int*)(ws+o);   o += (size_t)E;
    float* enorm  = ws+o;           o += (size_t)E;
    float* dinv   = ws+o;           o += (size_t)((N+7)&~7);
    float* h1     = ws+o;           o += (size_t)N*D1;
    float* hz     = ws+o;           o += (size_t)N*D2;
    (void)ws_size; (void)n_in; (void)out_size;

    hipMemsetAsync(rowacc, 0, (size_t)T*sizeof(float), stream);

    k_wimgB<<<dim3((12*64*64+255)/256), dim3(256), 0, stream>>>(Wih, img, cnt, N);
    k_deg  <<<dim3((E+255)/256), dim3(256), 0, stream>>>(dst, cnt, E);
    k_scan <<<dim3(1), dim3(256), 0, stream>>>(cnt, rowptr, rowcur, dinv, N, E);
    k_fill <<<dim3((E+255)/256), dim3(256), 0, stream>>>(src, dst, dinv, rowcur, esrc, enorm, E);
    k_h1   <<<dim3((N+3)/4), dim3(256), 0, stream>>>(x, W1, h1, N);
    k_gh   <<<dim3((N+1)/2), dim3(128), 0, stream>>>(h1, rowptr, esrc, enorm, dinv, b1, W2, hz, N);
    k_gath2<<<dim3(N), dim3(128), 0, stream>>>(hz, rowptr, esrc, enorm, dinv, b2, zbf, N);

    const int ntiles  = (T+63)/64;          // 1563
    const int ngroups = (ntiles+7)/8;       // 196
    k_big  <<<dim3(ngroups*32), dim3(64), 0, stream>>>(remb, img, zbf, b_ih, b_hh, trip, rowacc, T);
    k_sig  <<<dim3((T+255)/256), dim3(256), 0, stream>>>(rowacc, score, T);
}

// Round 15
// 306.427 us; speedup vs baseline: 1.5997x; 1.4762x over previous
//
#include <hip/hip_runtime.h>

#define NF 768
#define D1 10
#define D2 128
#define BM 64

typedef __attribute__((ext_vector_type(8))) short bf16x8;
typedef __attribute__((ext_vector_type(16))) float f32x16;

static __device__ __forceinline__ float sigf(float v){ return 1.0f/(1.0f+__expf(-v)); }
static __device__ __forceinline__ float tanhfast(float v){ return 2.0f/(1.0f+__expf(-2.0f*v)) - 1.0f; }
static __device__ __forceinline__ short f2bf(float f){
    unsigned u = __float_as_uint(f);
    u += 0x7fffu + ((u>>16)&1u);
    return (short)(u>>16);
}

static __device__ __forceinline__ void gload16(const void* g, void* l){
    __builtin_amdgcn_global_load_lds(
        (const __attribute__((address_space(1))) unsigned int*)(unsigned long long)g,
        (__attribute__((address_space(3))) unsigned int*)(unsigned long long)l,
        16, 0, 0);
}

static __device__ __forceinline__ short4 cvt4(float4 a){
    unsigned u0,u1;
    asm("v_cvt_pk_bf16_f32 %0, %1, %2" : "=v"(u0) : "v"(a.x), "v"(a.y));
    asm("v_cvt_pk_bf16_f32 %0, %1, %2" : "=v"(u1) : "v"(a.z), "v"(a.w));
    union { unsigned u[2]; short4 s; } r;
    r.u[0]=u0; r.u[1]=u1;
    return r.s;
}

// ---- degree counts ----
__global__ void k_deg(const int* __restrict__ dst, int* __restrict__ cnt, int E){
    int e = blockIdx.x*256 + threadIdx.x;
    if(e<E) atomicAdd(&cnt[dst[e]], 1);
}

// ---- scan + dinv, single block ----
__global__ __launch_bounds__(256) void k_scan(const int* __restrict__ cnt,
                                              int* __restrict__ rowptr, int* __restrict__ rowcur,
                                              float* __restrict__ dinv, int N, int E){
    __shared__ int part[256];
    int t = threadIdx.x;
    int C = (N+255)/256;
    int lo = t*C, hi = lo+C; if(hi>N) hi=N; if(lo>N) lo=N;
    int s=0;
    for(int i=lo;i<hi;i++) s += cnt[i];
    part[t]=s;
    __syncthreads();
    if(t==0){
        int run=0;
        for(int i=0;i<256;i++){ int v=part[i]; part[i]=run; run+=v; }
        rowptr[N]=E;
    }
    __syncthreads();
    int run = part[t];
    for(int i=lo;i<hi;i++){
        rowptr[i]=run; rowcur[i]=run; run += cnt[i];
        dinv[i] = rsqrtf((float)cnt[i] + 1.0f);
    }
}

__global__ void k_fill(const int* __restrict__ src, const int* __restrict__ dst,
                       const float* __restrict__ dinv, int* __restrict__ rowcur,
                       int* __restrict__ esrc, float* __restrict__ enorm, int E){
    int e = blockIdx.x*256 + threadIdx.x;
    if(e>=E) return;
    int s=src[e], d=dst[e];
    int pos = atomicAdd(&rowcur[d], 1);
    esrc[pos]=s;
    enorm[pos]=dinv[s]*dinv[d];
}

// ---- h1 = x @ W1 ----
__global__ __launch_bounds__(256) void k_h1(const float* __restrict__ x,
                                            const float* __restrict__ W1,
                                            float* __restrict__ h1, int N){
    __shared__ float wt[D1*NF];
    for(int idx=threadIdx.x; idx<NF*D1; idx+=256){
        int k=idx/D1, c=idx-k*D1;
        wt[c*NF+k]=W1[idx];
    }
    __syncthreads();
    int row = blockIdx.x*4 + (threadIdx.x>>6);
    int lane = threadIdx.x&63;
    if(row>=N) return;
    const float4* xr = (const float4*)(x + (size_t)row*NF);
    float acc[D1];
#pragma unroll
    for(int c=0;c<D1;c++) acc[c]=0.f;
#pragma unroll
    for(int i=0;i<3;i++){
        float4 v = xr[lane + 64*i];
#pragma unroll
        for(int c=0;c<D1;c++){
            float4 w = *(const float4*)&wt[c*NF + (lane+64*i)*4];
            acc[c] += v.x*w.x + v.y*w.y + v.z*w.z + v.w*w.w;
        }
    }
#pragma unroll
    for(int c=0;c<D1;c++){
        float v=acc[c];
#pragma unroll
        for(int off=32;off;off>>=1) v += __shfl_down(v,off,64);
        acc[c]=v;
    }
    if(lane==0){
#pragma unroll
        for(int c=0;c<D1;c++) h1[(size_t)row*D1+c]=acc[c];
    }
}

// ---- FUSED layer-1 gather + relu + hz = h @ W2 ----
__global__ __launch_bounds__(128) void k_gh(const float* __restrict__ h1,
        const int* __restrict__ rowptr, const int* __restrict__ esrc,
        const float* __restrict__ enorm, const float* __restrict__ dinv,
        const float* __restrict__ b1, const float* __restrict__ W2,
        float* __restrict__ hz, int N){
    __shared__ float w2s[D1*D2];
    int tid = threadIdx.x;
    for(int i=tid;i<D1*D2;i+=128) w2s[i]=W2[i];
    __syncthreads();
    int node = blockIdx.x*2 + (tid>>6);
    int lane = tid&63;
    if(node>=N) return;
    int e0=rowptr[node], e1=rowptr[node+1];
    float acc[D1];
#pragma unroll
    for(int c=0;c<D1;c++) acc[c]=0.f;
    for(int e=e0+lane; e<e1; e+=64){
        int s=esrc[e]; float w=enorm[e];
        const float* hr = h1 + (size_t)s*D1;
#pragma unroll
        for(int c=0;c<D1;c++) acc[c] += hr[c]*w;
    }
#pragma unroll
    for(int c=0;c<D1;c++){
        float v=acc[c];
#pragma unroll
        for(int off=32;off;off>>=1) v += __shfl_down(v,off,64);
        acc[c] = __shfl(v, 0, 64);
    }
    float di=dinv[node], d2=di*di;
    const float* hr = h1 + (size_t)node*D1;
    float h[D1];
#pragma unroll
    for(int c=0;c<D1;c++){
        float v = acc[c] + hr[c]*d2 + b1[c];
        h[c] = v>0.f ? v : 0.f;
    }
    float o0=0.f, o1=0.f;
#pragma unroll
    for(int k=0;k<D1;k++){
        o0 += h[k]*w2s[k*D2 + lane];
        o1 += h[k]*w2s[k*D2 + 64 + lane];
    }
    hz[(size_t)node*D2 + lane]      = o0;
    hz[(size_t)node*D2 + 64 + lane] = o1;
}

// ---- layer-2 CSR gather (fused zfin), fp32 z table ----
__global__ __launch_bounds__(128) void k_gath2(const float* __restrict__ hz,
        const int* __restrict__ rowptr, const int* __restrict__ esrc,
        const float* __restrict__ enorm, const float* __restrict__ dinv,
        const float* __restrict__ b2, float* __restrict__ zbf, int N){
    int n = blockIdx.x;
    int c = threadIdx.x;
    int e0 = rowptr[n], e1 = rowptr[n+1];
    float di = dinv[n];
    float acc = hz[(size_t)n*D2+c]*di*di + b2[c];
    int e = e0;
    for(; e+1<e1; e+=2){
        int s0=esrc[e], s1=esrc[e+1];
        float w0=enorm[e], w1=enorm[e+1];
        acc += hz[(size_t)s0*D2+c]*w0 + hz[(size_t)s1*D2+c]*w1;
    }
    if(e<e1) acc += hz[(size_t)esrc[e]*D2+c]*enorm[e];
    zbf[(size_t)n*D2+c] = acc;
}

// ---- B fragment image K=1024 (+ zero cnt) ----
__global__ void k_wimgB(const float* __restrict__ Wih, ushort* __restrict__ img,
                        int* __restrict__ cnt, int N){
    int gid = blockIdx.x*256 + threadIdx.x;        // 12*64*64 = 49152
    if(gid < N) cnt[gid] = 0;
    if(gid >= 12*64*64) return;
    int l = gid & 63;
    int ks16 = (gid>>6) & 63;
    int f = gid >> 12;
    int dd = l & 31, kb = l>>5;
    int wn = f/3, gi = f - wn*3;
    int gbase = (gi==0)?0:((gi==1)?256:384);
    int wrow = gbase + wn*32 + dd;
    int k = ks16*16 + kb*8;
    const float* p = Wih + (size_t)wrow*1024 + k;
    float4 v0=*(const float4*)p, v1=*(const float4*)(p+4);
    ushort o[8];
    o[0]=f2bf(v0.x); o[1]=f2bf(v0.y); o[2]=f2bf(v0.z); o[3]=f2bf(v0.w);
    o[4]=f2bf(v1.x); o[5]=f2bf(v1.y); o[6]=f2bf(v1.z); o[7]=f2bf(v1.w);
    *(int4*)(img + (size_t)gid*8) = *(int4*)o;
}

// ---- fused MFMA GEMM + LSTM partials. r10 structure (best measured: 177us)
// with conflict-free Ab layout [kh][row] (lane-linear frag reads) and
// rowacc-atomic epilogue. 4 waves, BK=16, A reg->cvt->LDS ring-2,
// B gload_lds ring-3, counted vmcnt, 1 barrier/step. ----
__global__ __launch_bounds__(256,3) void k_big(
    const float* __restrict__ remb, const ushort* __restrict__ img,
    const float* __restrict__ zbf, const float* __restrict__ b_ih,
    const float* __restrict__ b_hh, const int* __restrict__ trip,
    float* __restrict__ rowacc, int T)
{
    __shared__ ushort Ab[2][2*64*8];     // 2 x 2 KB: [slot][kh*64+row][8 bf16]
    __shared__ ushort Br[3][12*512];     // 3 x 12 KB
    int tid=threadIdx.x, lane=tid&63, w=tid>>6;
    int l31=lane&31, lh=lane>>5;
    int t0=blockIdx.x*BM;

    // A staging: lane -> row = w*16 + (lane>>2), asub = lane&3 (16B k-seg)
    const int arow = w*16 + (lane>>2);
    const int asub = lane&3;
    int tc = t0 + arow; if(tc>=T) tc=T-1;
    const float* pzh = zbf + (size_t)trip[3*tc]*D2   + asub*4;
    const float* prm = remb + (size_t)tc*NF          + asub*4;
    const float* pzt = zbf + (size_t)trip[3*tc+2]*D2 + asub*4;
    // conflict-free LDS write offset (ushorts): [kh=asub>>1][arow] 16B unit
    const int awoff = ((asub>>1)*64 + arow)*8 + (asub&1)*4;
    // frag read offsets (ushorts): lane-linear within each kh half
    const int ar0 = (lh*64 + l31)*8;
    const int ar1 = (lh*64 + 32 + l31)*8;

    f32x16 acc[2][3];
    const f32x16 zer = {0,0,0,0,0,0,0,0,0,0,0,0,0,0,0,0};
#pragma unroll
    for(int m=0;m<2;m++)
#pragma unroll
        for(int g=0;g<3;g++) acc[m][g]=zer;

    float4 pa[4];

#define ALOAD(C_) if((C_)<64){ \
    const float* s_; \
    if((C_)<8)       s_ = pzh + (C_)*16; \
    else if((C_)<56) s_ = prm + ((C_)-8)*16; \
    else             s_ = pzt + ((C_)-56)*16; \
    pa[(C_)&3] = *(const float4*)s_; }

#define AWRITE(C_) if((C_)<64){ \
    *(short4*)&Ab[(C_)&1][awoff] = cvt4(pa[(C_)&3]); }

#define BISSUE(C_) if((C_)<64){ \
    _Pragma("unroll") \
    for(int j_=0;j_<3;j_++){ \
        gload16(img + ((size_t)((w*3+j_)*64 + (C_))*64 + lane)*8, \
                &Br[(C_)%3][(w*3+j_)*512]); \
    } }

#define CH(C_,W_) { \
    asm volatile("s_waitcnt vmcnt(" W_ ")" ::: "memory"); \
    __builtin_amdgcn_sched_barrier(0); \
    asm volatile("s_waitcnt lgkmcnt(0)" ::: "memory"); \
    __builtin_amdgcn_s_barrier(); \
    __builtin_amdgcn_sched_barrier(0); \
    BISSUE((C_)+2) \
    __builtin_amdgcn_sched_barrier(0); \
    ALOAD((C_)+4) \
    __builtin_amdgcn_sched_barrier(0); \
    { \
        const ushort* a_ = &Ab[(C_)&1][0]; \
        const ushort* b_ = &Br[(C_)%3][0]; \
        bf16x8 A0_ = *(const bf16x8*)&a_[ar0]; \
        bf16x8 A1_ = *(const bf16x8*)&a_[ar1]; \
        bf16x8 B0_ = *(const bf16x8*)&b_[((w*3+0)*64+lane)*8]; \
        bf16x8 B1_ = *(const bf16x8*)&b_[((w*3+1)*64+lane)*8]; \
        bf16x8 B2_ = *(const bf16x8*)&b_[((w*3+2)*64+lane)*8]; \
        __builtin_amdgcn_s_setprio(1); \
        acc[0][0]=__builtin_amdgcn_mfma_f32_32x32x16_bf16(A0_,B0_,acc[0][0],0,0,0); \
        acc[0][1]=__builtin_amdgcn_mfma_f32_32x32x16_bf16(A0_,B1_,acc[0][1],0,0,0); \
        acc[0][2]=__builtin_amdgcn_mfma_f32_32x32x16_bf16(A0_,B2_,acc[0][2],0,0,0); \
        acc[1][0]=__builtin_amdgcn_mfma_f32_32x32x16_bf16(A1_,B0_,acc[1][0],0,0,0); \
        acc[1][1]=__builtin_amdgcn_mfma_f32_32x32x16_bf16(A1_,B1_,acc[1][1],0,0,0); \
        acc[1][2]=__builtin_amdgcn_mfma_f32_32x32x16_bf16(A1_,B2_,acc[1][2],0,0,0); \
        __builtin_amdgcn_s_setprio(0); \
    } \
    AWRITE((C_)+1) \
}

    // prologue: A(0..3) regs, B(0), B(1); write A(0)
    ALOAD(0) ALOAD(1) ALOAD(2) ALOAD(3)
    __builtin_amdgcn_sched_barrier(0);
    BISSUE(0) BISSUE(1)
    __builtin_amdgcn_sched_barrier(0);
    AWRITE(0)

    CH(0 ,"3") CH(1 ,"4") CH(2 ,"5") CH(3 ,"5") CH(4 ,"5") CH(5 ,"5") CH(6 ,"5") CH(7 ,"5")
    CH(8 ,"5") CH(9 ,"5") CH(10,"5") CH(11,"5") CH(12,"5") CH(13,"5") CH(14,"5") CH(15,"5")
    CH(16,"5") CH(17,"5") CH(18,"5") CH(19,"5") CH(20,"5") CH(21,"5") CH(22,"5") CH(23,"5")
    CH(24,"5") CH(25,"5") CH(26,"5") CH(27,"5") CH(28,"5") CH(29,"5") CH(30,"5") CH(31,"5")
    CH(32,"5") CH(33,"5") CH(34,"5") CH(35,"5") CH(36,"5") CH(37,"5") CH(38,"5") CH(39,"5")
    CH(40,"5") CH(41,"5") CH(42,"5") CH(43,"5") CH(44,"5") CH(45,"5") CH(46,"5") CH(47,"5")
    CH(48,"5") CH(49,"5") CH(50,"5") CH(51,"5") CH(52,"5") CH(53,"5") CH(54,"5") CH(55,"5")
    CH(56,"5") CH(57,"5") CH(58,"5") CH(59,"5") CH(60,"5") CH(61,"4") CH(62,"3") CH(63,"0")
#undef CH
#undef BISSUE
#undef AWRITE
#undef ALOAD

    // ---- epilogue: bias + LSTM + partial row-sums (global atomics) ----
    int d = w*32+l31;
    float bi=b_ih[d]+b_hh[d];
    float bg=b_ih[256+d]+b_hh[256+d];
    float bo=b_ih[384+d]+b_hh[384+d];
#pragma unroll
    for(int m=0;m<2;m++){
#pragma unroll
        for(int r=0;r<16;r++){
            int row = m*32 + (r&3)+8*(r>>2)+4*lh;
            int t = t0+row;
            float ov = 0.f;
            if(t<T){
                float ig = acc[m][0][r] + bi;
                float gg = acc[m][1][r] + bg;
                float og = acc[m][2][r] + bo;
                float cc = sigf(ig)*tanhfast(gg);
                ov = sigf(og)*tanhfast(cc);
            }
#pragma unroll
            for(int off=1; off<32; off<<=1) ov += __shfl_xor(ov, off, 64);
            if(l31==0 && t<T) atomicAdd(&rowacc[t], ov);
        }
    }
}

__global__ void k_sig(const float* __restrict__ rowacc, float* __restrict__ score, int T){
    int t = blockIdx.x*256 + threadIdx.x;
    if(t<T) score[t] = sigf(rowacc[t]);
}

extern "C" void kernel_launch(void* const* d_in, const int* in_sizes, int n_in,
                              void* d_out, int out_size, void* d_ws, size_t ws_size,
                              hipStream_t stream){
    const float* x    = (const float*)d_in[0];
    const float* remb = (const float*)d_in[1];
    const float* W1   = (const float*)d_in[2];
    const float* b1   = (const float*)d_in[3];
    const float* W2   = (const float*)d_in[4];
    const float* b2   = (const float*)d_in[5];
    const float* Wih  = (const float*)d_in[6];
    const float* b_ih = (const float*)d_in[8];
    const float* b_hh = (const float*)d_in[9];
    const int*   ei   = (const int*)d_in[10];
    const int*   trip = (const int*)d_in[11];
    float* score = (float*)d_out;

    const int N = in_sizes[0]/NF;       // 15000
    const int E = in_sizes[10]/2;       // 200000
    const int T = in_sizes[11]/3;       // 100000
    const int* src = ei;
    const int* dst = ei + E;

    float* ws = (float*)d_ws;
    size_t o = 0;
    ushort* img  = (ushort*)(ws+o); o += (size_t)12*64*64*8/2;   // 786 KB
    float* zbf   = ws+o;            o += (size_t)N*D2;           // fp32 z
    float* rowacc= ws+o;            o += (size_t)((T+7)&~7);
    int*   cnt    = (int*)(ws+o);   o += (size_t)((N+8)&~7);
    int*   rowptr = (int*)(ws+o);   o += (size_t)((N+8)&~7);
    int*   rowcur = (int*)(ws+o);   o += (size_t)((N+8)&~7);
    int*   esrc   = (int*)(ws+o);   o += (size_t)E;
    float* enorm  = ws+o;           o += (size_t)E;
    float* dinv   = ws+o;           o += (size_t)((N+7)&~7);
    float* h1     = ws+o;           o += (size_t)N*D1;
    float* hz     = ws+o;           o += (size_t)N*D2;
    (void)ws_size; (void)n_in; (void)out_size;

    hipMemsetAsync(rowacc, 0, (size_t)T*sizeof(float), stream);

    k_wimgB<<<dim3((12*64*64+255)/256), dim3(256), 0, stream>>>(Wih, img, cnt, N);
    k_deg  <<<dim3((E+255)/256), dim3(256), 0, stream>>>(dst, cnt, E);
    k_scan <<<dim3(1), dim3(256), 0, stream>>>(cnt, rowptr, rowcur, dinv, N, E);
    k_fill <<<dim3((E+255)/256), dim3(256), 0, stream>>>(src, dst, dinv, rowcur, esrc, enorm, E);
    k_h1   <<<dim3((N+3)/4), dim3(256), 0, stream>>>(x, W1, h1, N);
    k_gh   <<<dim3((N+1)/2), dim3(128), 0, stream>>>(h1, rowptr, esrc, enorm, dinv, b1, W2, hz, N);
    k_gath2<<<dim3(N), dim3(128), 0, stream>>>(hz, rowptr, esrc, enorm, dinv, b2, zbf, N);
    k_big  <<<dim3((T+BM-1)/BM), dim3(256), 0, stream>>>(remb, img, zbf, b_ih, b_hh, trip, rowacc, T);
    k_sig  <<<dim3((T+255)/256), dim3(256), 0, stream>>>(rowacc, score, T);
}